// Round 20
// baseline (919.712 us; speedup 1.0000x reference)
//
#include <hip/hip_runtime.h>
#include <hip/hip_bf16.h>
#include <hip/hip_cooperative_groups.h>

namespace cg = cooperative_groups;

#define NU 4096
#define NI 4096
#define NE 262144
#define NPRED 65536
#define DD 64
#define KCL 1000
#define UNUM 50000
#define INUM 25000
#define INUM_PAD 25008
#define KCL_PAD 1008

typedef short sh8 __attribute__((ext_vector_type(8)));
typedef float f4 __attribute__((ext_vector_type(4)));

__device__ __forceinline__ float wred64(float x){
#pragma unroll
  for(int m=1;m<64;m<<=1) x += __shfl_xor(x,m);
  return x;
}

__device__ __forceinline__ float fast_exp2(float x){
  return __builtin_amdgcn_exp2f(x);
}

__device__ __forceinline__ int aload_i(const int* p){
  return __hip_atomic_load(p, __ATOMIC_RELAXED, __HIP_MEMORY_SCOPE_AGENT);
}
__device__ __forceinline__ float aload_f(const float* p){
  return __hip_atomic_load(p, __ATOMIC_RELAXED, __HIP_MEMORY_SCOPE_AGENT);
}

// ================= cooperative mega-kernel: whole sequential front-end ====
// phases (grid.sync between each):
//  0: zero cnt_u/cnt_i/tot4
//  1: degree hist (vb<1024) + static-table norms (atomic vs HBM pipes)
//  2: exclusive scan (2 blocks, 256 thr x 16) -> rp, cur, inv
//  3: CSR fill (vb<1024) + gather/init e,res,hsA
//  4,5,6: conv layers (6: fused norms+pos epilogue)
// Uniform loads of in-kernel-written data (rp, inv) use agent-scope atomic
// loads (vector path; scalar K$ is not reliably invalidated -> R5-class bug).
#define HB 1024
#define HN0 (HB+12500)        // ntb_user  (50000 rows /4)
#define HN1 (HN0+6252)        // ntb_item  (25008 padded /4)
#define HN2 (HN1+252)         // ncb_u     (1008 padded /4)
#define HN3 (HN2+252)         // ncb_i     (1008 padded /4)
#define MGRID 1024

struct MArg {
  const int *eu, *ev;
  int *cnt_u, *cnt_i, *rp_u, *rp_i, *cur_u, *cur_i, *adj_u, *adj_i;
  float *inv_u, *inv_i;
  const float *emb_u, *emb_i, *ucent, *icent;
  const int *idx_u, *idx_i, *u2c, *i2c;
  float *e_u, *e_i, *h_u, *h_i, *hsA_u, *hsA_i, *hsB_u, *hsB_i, *res_u, *res_i;
  __hip_bfloat16 *ntb_u, *ntb_i, *ncb_u, *ncb_i, *nc_u, *nc_i, *npv_u, *npv_i;
  float *tot4, *pos4;
};

__device__ void conv_phase(const MArg& a, int bid, int tid,
                           const float* hsu_in, const float* hsi_in,
                           float* hsu_out, float* hsi_out, int last){
  int lane = tid & 63;
  for(int vb = bid; vb < 2048; vb += MGRID){
    int b = vb*4 + (tid>>6);
    const int* rp; const int* adj; const float* srcv; const float* inv;
    float *h, *res, *hso; int node;
    const float* eX; const float* cent; const int* idxX; const int* n2c;
    __hip_bfloat16 *nc, *npv; float *posA, *posB;
    if(b < NI){
      rp=a.rp_i; adj=a.adj_i; srcv=hsu_in; inv=a.inv_i; h=a.h_i; res=a.res_i; hso=hsi_out; node=b;
      eX=a.e_i; cent=a.icent; idxX=a.idx_i; n2c=a.i2c; nc=a.nc_i; npv=a.npv_i;
      posA=a.pos4+1*NU; posB=a.pos4+3*NU;
    } else {
      node=b-NI; rp=a.rp_u; adj=a.adj_u; srcv=hsi_in; inv=a.inv_u; h=a.h_u; res=a.res_u; hso=hsu_out;
      eX=a.e_u; cent=a.ucent; idxX=a.idx_u; n2c=a.u2c; nc=a.nc_u; npv=a.npv_u;
      posA=a.pos4+0*NU; posB=a.pos4+2*NU;
    }
    int s=aload_i(&rp[node]), e=aload_i(&rp[node+1]);
    float acc=0.f;
    for(int base=s; base<e; base+=64){
      int m = e-base;
      int myidx = adj[base + min(lane, m-1)];   // coalesced vector load
      int kk = min(64, m);
      int k=0;
      for(; k+8<=kk; k+=8){
        int i0=__shfl(myidx,k  ), i1=__shfl(myidx,k+1),
            i2=__shfl(myidx,k+2), i3=__shfl(myidx,k+3),
            i4=__shfl(myidx,k+4), i5=__shfl(myidx,k+5),
            i6=__shfl(myidx,k+6), i7=__shfl(myidx,k+7);
        float v0=srcv[i0*DD+lane], v1=srcv[i1*DD+lane],
              v2=srcv[i2*DD+lane], v3=srcv[i3*DD+lane],
              v4=srcv[i4*DD+lane], v5=srcv[i5*DD+lane],
              v6=srcv[i6*DD+lane], v7=srcv[i7*DD+lane];
        acc += ((v0+v1)+(v2+v3)) + ((v4+v5)+(v6+v7));
      }
      for(; k<kk; k++) acc += srcv[__shfl(myidx,k)*DD+lane];
    }
    float iv = aload_f(&inv[node]);
    float outv = acc*iv;
    h[node*DD+lane] = outv;
    res[node*DD+lane] += outv;
    if(!last){
      hso[node*DD+lane] = outv*iv;
    } else {
      const float SC = 14.426950408889634f;
      const float eps = 1e-12f;
      float ev = eX[node*DD+lane];
      float hn = wred64(outv*outv);
      float en = wred64(ev*ev);
      float ihn = 1.0f/fmaxf(sqrtf(hn), eps);
      float ien = 1.0f/fmaxf(sqrtf(en), eps);
      nc [node*DD+lane] = __float2bfloat16(outv*(SC*ihn));
      npv[node*DD+lane] = __float2bfloat16(ev  *(SC*ien));
      int c = n2c[idxX[node]];
      float cv = cent[c*DD+lane];
      float he = wred64(outv*ev);
      float cc = wred64(cv*cv);
      float ec = wred64(ev*cv);
      if(lane==0){
        float icn = 1.0f/fmaxf(sqrtf(cc), eps);
        posA[node] = he*ihn*ien;
        posB[node] = ec*ien*icn;
      }
    }
  }
}

__global__ __launch_bounds__(256,4)
void k_mega(MArg a){
  cg::grid_group grid = cg::this_grid();
  int bid = blockIdx.x, tid = threadIdx.x;
  int lane = tid & 63;

  // phase 0: zero cnt + tot4
  {
    int i = bid*256 + tid;
    if(i < NU) a.cnt_u[i] = 0;
    else if(i < 2*NU) a.cnt_i[i-NU] = 0;
    else if(i < 6*NU) a.tot4[i-2*NU] = 0.f;
    if(i < 6*NU){  // second strip (grid covers 262144 >> 24576; one pass each)
    }
  }
  grid.sync();

  // phase 1: hist + static norms
  for(int vb = bid; vb < HN3; vb += MGRID){
    if(vb < HB){
      int t = vb*256 + tid;
      atomicAdd(&a.cnt_u[a.eu[t]],1); atomicAdd(&a.cnt_i[a.ev[t]],1);
    } else {
      const float* in; __hip_bfloat16* outp; int rows; int base;
      if(vb < HN0)      { in=a.emb_u; outp=a.ntb_u; rows=UNUM; base=HB; }
      else if(vb < HN1) { in=a.emb_i; outp=a.ntb_i; rows=INUM; base=HN0; }
      else if(vb < HN2) { in=a.ucent; outp=a.ncb_u; rows=KCL;  base=HN1; }
      else              { in=a.icent; outp=a.ncb_i; rows=KCL;  base=HN2; }
      int row = (vb-base)*4 + (tid>>6);
      if(row >= rows){
        outp[row*DD + lane] = __float2bfloat16(0.f);
      } else {
        float v = in[row*DD + lane];
        float s = wred64(v*v);
        float sc = 1.0f / fmaxf(sqrtf(s), 1e-12f);
        outp[row*DD + lane] = __float2bfloat16(v*sc);
      }
    }
  }
  grid.sync();

  // phase 2: exclusive scan (2 blocks, 256 thr x 16 counts each)
  if(bid < 2){
    const int* cnt = bid ? a.cnt_i : a.cnt_u;
    int* rp  = bid ? a.rp_i  : a.rp_u;
    int* cur = bid ? a.cur_i : a.cur_u;
    float* inv = bid ? a.inv_i : a.inv_u;
    __shared__ int sdata[256];
    int v[16]; int s = 0;
#pragma unroll
    for(int k=0;k<16;k++){ v[k]=cnt[tid*16+k]; s+=v[k]; }
    sdata[tid]=s; __syncthreads();
    for(int off=1; off<256; off<<=1){
      int add = (tid>=off)? sdata[tid-off] : 0;
      __syncthreads();
      if(tid>=off) sdata[tid] += add;
      __syncthreads();
    }
    int run = sdata[tid]-s;
#pragma unroll
    for(int k=0;k<16;k++){
      int idx = tid*16+k;
      rp[idx]=run; cur[idx]=run;
      inv[idx] = 1.0f/sqrtf(fmaxf((float)v[k],1.0f));
      run += v[k];
    }
    if(tid==255) rp[4096]=run;
  }
  grid.sync();

  // phase 3: CSR fill + gather/init
  for(int vb = bid; vb < 3072; vb += MGRID){
    if(vb < 1024){
      int t = vb*256 + tid;
      int u=a.eu[t], v=a.ev[t];
      a.adj_u[atomicAdd(&a.cur_u[u],1)] = v;
      a.adj_i[atomicAdd(&a.cur_i[v],1)] = u;
    } else {
      int t = (vb-1024)*256 + tid;
      const int half = NU*DD;
      if(t < half){
        int r=t>>6;
        float v = a.emb_u[a.idx_u[r]*DD + (t&63)];
        float iv = aload_f(&a.inv_u[r]);
        a.e_u[t]=v; a.res_u[t]=v; a.hsA_u[t]=v*iv;
      } else {
        int s2=t-half; int r=s2>>6;
        float v = a.emb_i[a.idx_i[r]*DD + (s2&63)];
        float iv = aload_f(&a.inv_i[r]);
        a.e_i[s2]=v; a.res_i[s2]=v; a.hsA_i[s2]=v*iv;
      }
    }
  }
  grid.sync();

  // phases 4-6: conv layers (A->B, B->A, A->last+epilogue)
  conv_phase(a, bid, tid, a.hsA_u, a.hsA_i, a.hsB_u, a.hsB_i, 0);
  grid.sync();
  conv_phase(a, bid, tid, a.hsB_u, a.hsB_i, a.hsA_u, a.hsA_i, 0);
  grid.sync();
  conv_phase(a, bid, tid, a.hsA_u, a.hsA_i, a.hsB_u, a.hsB_i, 1);
}

// ---- fused MFMA exp-sum (z=0..3) + scores (z=4); 128 A-rows per wave ----
// R19-bench version (banked, 74.5us): two t-halves with explicit c[4] so
// 8 MFMAs issue back-to-back, then 16 exps stream at trans rate.
// jchunk=512 -> 1208 working blocks. XCD-pinned decomposition.
// tot[b] += sum_j exp2(dot(A[b],B[j])), A pre-scaled by SC = 10*log2(e).
// B buffers have >=48 rows of slack past nBpad (depth-1 prefetch overrun).
struct EArg {
  const __hip_bfloat16* A; const __hip_bfloat16* B; float* tot;
  int nBpad; int jchunk; int ny;
};
struct SArg {
  const float* res_u; const float* res_i;
  const int* pu; const int* pv; const int* nu; const int* nv; float* out;
};
#define EGX 784

__global__ __launch_bounds__(256,4)
void k_expsum(EArg e0, EArg e1, EArg e2, EArg e3, SArg sc){
  if(blockIdx.z == 4){
    const int stride = EGX*256;
    const int limit = 2*NPRED*16;
    for(int t = blockIdx.x*256 + threadIdx.x; t < limit; t += stride){
      int pair = t >> 4;
      int sl = t & 15;
      int a,b;
      if(pair < NPRED){ a=sc.pu[pair]; b=sc.pv[pair]; }
      else { a=sc.nu[pair-NPRED]; b=sc.nv[pair-NPRED]; }
      f4 xu = *(const f4*)(sc.res_u + a*DD + sl*4);
      f4 xv = *(const f4*)(sc.res_i + b*DD + sl*4);
      float x = xu[0]*xv[0] + xu[1]*xv[1] + xu[2]*xv[2] + xu[3]*xv[3];
      x += __shfl_xor(x,1); x += __shfl_xor(x,2);
      x += __shfl_xor(x,4); x += __shfl_xor(x,8);
      if(sl==0) sc.out[pair] = x*(1.0f/16.0f);
    }
    return;
  }
  EArg e = (blockIdx.z==0)? e0 : (blockIdx.z==1)? e1 : (blockIdx.z==2)? e2 : e3;
  int bid = blockIdx.x;
  int g = bid >> 6, r6 = bid & 63;
  int y = 8*g + (r6 & 7);
  int x = r6 >> 3;
  if(y >= e.ny) return;
  int wave = threadIdx.x >> 6;
  int lane = threadIdx.x & 63;
  int row0 = (x*4 + wave)*128;
  int j_begin = y*e.jchunk;
  int j_end = min(j_begin + e.jchunk, e.nBpad);
  int r = lane & 15, kq = (lane>>4)*8;

  sh8 a0[8], a1[8];
#pragma unroll
  for(int t=0;t<8;t++){
    const short* ap = (const short*)(e.A + (row0 + t*16 + r)*DD);
    a0[t] = *(const sh8*)(ap + kq);
    a1[t] = *(const sh8*)(ap + kq + 32);
  }
  float acc[8][4];
#pragma unroll
  for(int t=0;t<8;t++)
#pragma unroll
    for(int q=0;q<4;q++) acc[t][q]=0.f;

  const short* bbase = (const short*)e.B;
  const short* bp0 = bbase + (j_begin + r)*DD + kq;
  sh8 b0 = *(const sh8*)(bp0);
  sh8 b1 = *(const sh8*)(bp0 + 32);

#pragma unroll 2
  for(int j0=j_begin; j0<j_end; j0+=16){
    const short* np = bbase + (j0 + 16 + r)*DD + kq;
    sh8 n0 = *(const sh8*)(np);
    sh8 n1 = *(const sh8*)(np + 32);
    {
      f4 c[4];
#pragma unroll
      for(int t=0;t<4;t++){
        f4 cc = {0.f,0.f,0.f,0.f};
        cc = __builtin_amdgcn_mfma_f32_16x16x32_bf16(a0[t], b0, cc, 0,0,0);
        c[t] = __builtin_amdgcn_mfma_f32_16x16x32_bf16(a1[t], b1, cc, 0,0,0);
      }
#pragma unroll
      for(int t=0;t<4;t++)
#pragma unroll
        for(int q=0;q<4;q++) acc[t][q] += fast_exp2(c[t][q]);
    }
    {
      f4 c[4];
#pragma unroll
      for(int t=0;t<4;t++){
        f4 cc = {0.f,0.f,0.f,0.f};
        cc = __builtin_amdgcn_mfma_f32_16x16x32_bf16(a0[t+4], b0, cc, 0,0,0);
        c[t] = __builtin_amdgcn_mfma_f32_16x16x32_bf16(a1[t+4], b1, cc, 0,0,0);
      }
#pragma unroll
      for(int t=0;t<4;t++)
#pragma unroll
        for(int q=0;q<4;q++) acc[t+4][q] += fast_exp2(c[t][q]);
    }
    b0 = n0; b1 = n1;
  }
#pragma unroll
  for(int t=0;t<8;t++){
#pragma unroll
    for(int q=0;q<4;q++){
      float v = acc[t][q];
      v += __shfl_xor(v,1); v += __shfl_xor(v,2);
      v += __shfl_xor(v,4); v += __shfl_xor(v,8);
      if(r==0) atomicAdd(&e.tot[row0 + t*16 + (lane>>4)*4 + q], v);
    }
  }
}

// ---- final losses (pad rows each contributed exp2(0)=1 -> subtract) ----
__global__ void k_loss(const float* __restrict__ tot4, const float* __restrict__ pos4,
                       float* out){
  const float PI_ = (float)(INUM_PAD-INUM);   // 8
  const float PK_ = (float)(KCL_PAD-KCL);     // 8
  float s0=0,s1=0,s2=0,s3=0;
  for(int b=threadIdx.x; b<NU; b+=256){
    s0 += logf(tot4[0*NU+b])       - 10.f*pos4[0*NU+b];
    s1 += logf(tot4[1*NU+b] - PI_) - 10.f*pos4[1*NU+b];
    s2 += logf(tot4[2*NU+b] - PK_) - 10.f*pos4[2*NU+b];
    s3 += logf(tot4[3*NU+b] - PK_) - 10.f*pos4[3*NU+b];
  }
  s0=wred64(s0); s1=wred64(s1); s2=wred64(s2); s3=wred64(s3);
  __shared__ float ls[4][4];
  int lane=threadIdx.x&63, w=threadIdx.x>>6;
  if(lane==0){ ls[w][0]=s0; ls[w][1]=s1; ls[w][2]=s2; ls[w][3]=s3; }
  __syncthreads();
  if(threadIdx.x==0){
    float a=0,b2=0,c=0,d=0;
#pragma unroll
    for(int k=0;k<4;k++){ a+=ls[k][0]; b2+=ls[k][1]; c+=ls[k][2]; d+=ls[k][3]; }
    out[2*NPRED]   = 1e-6f*(a+b2);
    out[2*NPRED+1] = 8e-8f*(c+d);
  }
}

extern "C" void kernel_launch(void* const* d_in, const int* in_sizes, int n_in,
                              void* d_out, int out_size, void* d_ws, size_t ws_size,
                              hipStream_t stream) {
  const float* emb_user = (const float*)d_in[0];
  const float* emb_item = (const float*)d_in[1];
  const float* ucent    = (const float*)d_in[2];
  const float* icent    = (const float*)d_in[3];
  const int* edge_u = (const int*)d_in[4];
  const int* edge_v = (const int*)d_in[5];
  const int* pos_u  = (const int*)d_in[6];
  const int* pos_v  = (const int*)d_in[7];
  const int* neg_u  = (const int*)d_in[8];
  const int* neg_v  = (const int*)d_in[9];
  const int* idx_u  = (const int*)d_in[10];
  const int* idx_i  = (const int*)d_in[11];
  const int* u2c    = (const int*)d_in[12];
  const int* i2c    = (const int*)d_in[13];
  float* out = (float*)d_out;

  char* w = (char*)d_ws;
  auto alloc = [&](size_t bytes)->void*{
    void* p = (void*)w;
    w += (bytes + 255) & ~(size_t)255;
    return p;
  };
  int* cnt_u = (int*)alloc(NU*4);
  int* cnt_i = (int*)alloc(NI*4);
  int* rp_u  = (int*)alloc((NU+1)*4);
  int* rp_i  = (int*)alloc((NI+1)*4);
  int* cur_u = (int*)alloc(NU*4);
  int* cur_i = (int*)alloc(NI*4);
  int* adj_u = (int*)alloc((size_t)NE*4);
  int* adj_i = (int*)alloc((size_t)NE*4);
  float* inv_u = (float*)alloc(NU*4);
  float* inv_i = (float*)alloc(NI*4);
  float* e_u  = (float*)alloc((size_t)NU*DD*4);
  float* e_i  = (float*)alloc((size_t)NI*DD*4);
  float* h_u  = (float*)alloc((size_t)NU*DD*4);
  float* h_i  = (float*)alloc((size_t)NI*DD*4);
  float* hsA_u = (float*)alloc((size_t)NU*DD*4);
  float* hsA_i = (float*)alloc((size_t)NI*DD*4);
  float* hsB_u = (float*)alloc((size_t)NU*DD*4);
  float* hsB_i = (float*)alloc((size_t)NI*DD*4);
  float* res_u= (float*)alloc((size_t)NU*DD*4);
  float* res_i= (float*)alloc((size_t)NI*DD*4);
  __hip_bfloat16* ntb_user = (__hip_bfloat16*)alloc((size_t)(UNUM+48)*DD*2);
  __hip_bfloat16* ntb_item = (__hip_bfloat16*)alloc((size_t)(INUM_PAD+48)*DD*2);
  __hip_bfloat16* ncb_u = (__hip_bfloat16*)alloc((size_t)(KCL_PAD+48)*DD*2);
  __hip_bfloat16* ncb_i = (__hip_bfloat16*)alloc((size_t)(KCL_PAD+48)*DD*2);
  __hip_bfloat16* nc_u  = (__hip_bfloat16*)alloc((size_t)NU*DD*2);
  __hip_bfloat16* nc_i  = (__hip_bfloat16*)alloc((size_t)NI*DD*2);
  __hip_bfloat16* npv_u = (__hip_bfloat16*)alloc((size_t)NU*DD*2);
  __hip_bfloat16* npv_i = (__hip_bfloat16*)alloc((size_t)NI*DD*2);
  float* tot4 = (float*)alloc(4*NU*4);
  float* pos4 = (float*)alloc(4*NU*4);

  MArg m = {
    edge_u, edge_v,
    cnt_u, cnt_i, rp_u, rp_i, cur_u, cur_i, adj_u, adj_i,
    inv_u, inv_i,
    emb_user, emb_item, ucent, icent,
    idx_u, idx_i, u2c, i2c,
    e_u, e_i, h_u, h_i, hsA_u, hsA_i, hsB_u, hsB_i, res_u, res_i,
    ntb_user, ntb_item, ncb_u, ncb_i, nc_u, nc_i, npv_u, npv_i,
    tot4, pos4
  };
  void* kargs[] = { (void*)&m };
  hipLaunchCooperativeKernel((const void*)k_mega, dim3(MGRID), dim3(256),
                             kargs, 0, stream);

  EArg eu_ = { nc_u,  ntb_user, tot4 + 0*NU, UNUM,     512, 98 };
  EArg ei_ = { nc_i,  ntb_item, tot4 + 1*NU, INUM_PAD, 512, 49 };
  EArg ep0 = { npv_u, ncb_u,    tot4 + 2*NU, KCL_PAD,  48,  21 };
  EArg ep1 = { npv_i, ncb_i,    tot4 + 3*NU, KCL_PAD,  48,  21 };
  SArg sc  = { res_u, res_i, pos_u, pos_v, neg_u, neg_v, out };
  k_expsum<<<dim3(EGX,1,5), 256, 0, stream>>>(eu_, ei_, ep0, ep1, sc);

  k_loss<<<1, 256, 0, stream>>>(tot4, pos4, out);
}

// Round 21
// 299.709 us; speedup vs baseline: 3.0687x; 3.0687x over previous
//
#include <hip/hip_runtime.h>
#include <hip/hip_bf16.h>

#define NU 4096
#define NI 4096
#define NE 262144
#define NPRED 65536
#define DD 64
#define KCL 1000
#define UNUM 50000
#define INUM 25000
#define INUM_PAD 25008
#define KCL_PAD 1008

typedef short sh8 __attribute__((ext_vector_type(8)));
typedef float f4 __attribute__((ext_vector_type(4)));

__device__ __forceinline__ float wred64(float x){
#pragma unroll
  for(int m=1;m<64;m<<=1) x += __shfl_xor(x,m);
  return x;
}

__device__ __forceinline__ float fast_exp2(float x){
  return __builtin_amdgcn_exp2f(x);
}

// ---- fused: degree histogram (blocks 0..1023) + static-table norms ----
#define HB 1024
#define HN0 (HB+12500)        // ntb_user  (50000 rows /4)
#define HN1 (HN0+6252)        // ntb_item  (25008 padded /4)
#define HN2 (HN1+252)         // ncb_u     (1008 padded /4)
#define HN3 (HN2+252)         // ncb_i     (1008 padded /4)

__global__ void k_histnorm(const int* __restrict__ eu, const int* __restrict__ ev,
                           int* cu, int* ci,
                           const float* __restrict__ emb_u, const float* __restrict__ emb_i,
                           const float* __restrict__ ucent, const float* __restrict__ icent,
                           __hip_bfloat16* ntb_u, __hip_bfloat16* ntb_i,
                           __hip_bfloat16* ncb_u, __hip_bfloat16* ncb_i){
  int b = blockIdx.x;
  if(b < HB){
    int t = b*256 + threadIdx.x;
    atomicAdd(&cu[eu[t]],1); atomicAdd(&ci[ev[t]],1);
    return;
  }
  const float* in; __hip_bfloat16* outp; int rows; int base;
  if(b < HN0)      { in=emb_u; outp=ntb_u; rows=UNUM; base=HB; }
  else if(b < HN1) { in=emb_i; outp=ntb_i; rows=INUM; base=HN0; }
  else if(b < HN2) { in=ucent; outp=ncb_u; rows=KCL;  base=HN1; }
  else             { in=icent; outp=ncb_i; rows=KCL;  base=HN2; }
  int row = (b-base)*4 + (threadIdx.x>>6);
  int lane = threadIdx.x & 63;
  if(row >= rows){ outp[row*DD + lane] = __float2bfloat16(0.f); return; }
  float v = in[row*DD + lane];
  float s = wred64(v*v);
  float sc = 1.0f / fmaxf(sqrtf(s), 1e-12f);
  outp[row*DD + lane] = __float2bfloat16(v*sc);
}

// ---- exclusive scan over 4096 counts (one block per side) + tot4 zeroing ----
__global__ void k_scan(const int* cnt_u, int* rp_u, int* cur_u, float* inv_u,
                       const int* cnt_i, int* rp_i, int* cur_i, float* inv_i,
                       float* tot4){
  {
    int base = blockIdx.x*8192 + threadIdx.x*8;
#pragma unroll
    for(int k=0;k<8;k++) tot4[base+k] = 0.f;
  }
  const int* cnt = blockIdx.x ? cnt_i : cnt_u;
  int* rp  = blockIdx.x ? rp_i  : rp_u;
  int* cur = blockIdx.x ? cur_i : cur_u;
  float* inv = blockIdx.x ? inv_i : inv_u;
  __shared__ int sdata[1024];
  int tid = threadIdx.x;
  int v[4]; int s = 0;
#pragma unroll
  for(int k=0;k<4;k++){ v[k]=cnt[tid*4+k]; s+=v[k]; }
  sdata[tid]=s; __syncthreads();
  for(int off=1; off<1024; off<<=1){
    int add = (tid>=off)? sdata[tid-off] : 0;
    __syncthreads();
    if(tid>=off) sdata[tid] += add;
    __syncthreads();
  }
  int run = sdata[tid]-s;   // exclusive base
#pragma unroll
  for(int k=0;k<4;k++){
    int idx = tid*4+k;
    rp[idx]=run; cur[idx]=run;
    inv[idx] = 1.0f/sqrtf(fmaxf((float)v[k],1.0f));
    run += v[k];
  }
  if(tid==1023) rp[4096]=run;
}

// ---- fused CSR fill (blocks 0..1023) + gather/init (blocks 1024..3071) ----
__global__ void k_fillgather(const int* __restrict__ eu, const int* __restrict__ ev,
                             int* cur_u, int* cur_i, int* adj_u, int* adj_i,
                             const float* __restrict__ emb_u, const float* __restrict__ emb_i,
                             const int* __restrict__ idx_u, const int* __restrict__ idx_i,
                             const float* __restrict__ inv_u, const float* __restrict__ inv_i,
                             float* e_u, float* e_i, float* res_u, float* res_i,
                             float* hs_u, float* hs_i){
  int b = blockIdx.x;
  if(b < 1024){
    int t = b*256 + threadIdx.x;
    int u=eu[t], v=ev[t];
    adj_u[atomicAdd(&cur_u[u],1)] = v;
    adj_i[atomicAdd(&cur_i[v],1)] = u;
  } else {
    int t = (b-1024)*256 + threadIdx.x;
    const int half = NU*DD;
    if(t < half){
      int r=t>>6;
      float v = emb_u[idx_u[r]*DD + (t&63)];
      e_u[t]=v; res_u[t]=v; hs_u[t]=v*inv_u[r];
    } else {
      int s=t-half; int r=s>>6;
      float v = emb_i[idx_i[r]*DD + (s&63)];
      e_i[s]=v; res_i[s]=v; hs_i[s]=v*inv_i[r];
    }
  }
}

// ---- pull-style conv: 4 waves per block, one node per wave ----
// adj content differs call-to-call (atomic fill order), so adj MUST be read
// through the vector path (coalesced per-lane load + shfl broadcast), never
// scalar s_load (K$ staleness across graph replays = nondeterministic output).
// last=1 (layer 3): fused epilogue computes nc (SC*normalize(h)),
// npv (SC*normalize(e)) and this side's pos4 entries; skips hs_next write.
__global__ void k_conv(const int* __restrict__ rp_i, const int* __restrict__ adj_i,
                       const float* __restrict__ hsu_in, const float* __restrict__ inv_i,
                       float* h_i, float* res_i, float* hsi_out,
                       const int* __restrict__ rp_u, const int* __restrict__ adj_u,
                       const float* __restrict__ hsi_in, const float* __restrict__ inv_u,
                       float* h_u, float* res_u, float* hsu_out,
                       const float* __restrict__ e_u, const float* __restrict__ e_i,
                       const float* __restrict__ ucent, const float* __restrict__ icent,
                       const int* __restrict__ idx_u, const int* __restrict__ idx_i,
                       const int* __restrict__ u2c, const int* __restrict__ i2c,
                       __hip_bfloat16* nc_u, __hip_bfloat16* nc_i,
                       __hip_bfloat16* npv_u, __hip_bfloat16* npv_i,
                       float* pos4, int last){
  int b = blockIdx.x*4 + (threadIdx.x>>6);
  int lane = threadIdx.x & 63;
  const int* rp; const int* adj; const float* srcv; const float* inv;
  float *h, *res, *hso; int node;
  const float* eX; const float* cent; const int* idxX; const int* n2c;
  __hip_bfloat16 *nc, *npv; float *posA, *posB;
  if(b < NI){
    rp=rp_i; adj=adj_i; srcv=hsu_in; inv=inv_i; h=h_i; res=res_i; hso=hsi_out; node=b;
    eX=e_i; cent=icent; idxX=idx_i; n2c=i2c; nc=nc_i; npv=npv_i;
    posA=pos4+1*NU; posB=pos4+3*NU;
  } else {
    node=b-NI; rp=rp_u; adj=adj_u; srcv=hsi_in; inv=inv_u; h=h_u; res=res_u; hso=hsu_out;
    eX=e_u; cent=ucent; idxX=idx_u; n2c=u2c; nc=nc_u; npv=npv_u;
    posA=pos4+0*NU; posB=pos4+2*NU;
  }
  int s=rp[node], e=rp[node+1];
  float acc=0.f;
  for(int base=s; base<e; base+=64){
    int m = e-base;
    int myidx = adj[base + min(lane, m-1)];   // one coalesced vector load / 64 edges
    int kk = min(64, m);
    int k=0;
    for(; k+8<=kk; k+=8){
      int i0=__shfl(myidx,k  ), i1=__shfl(myidx,k+1),
          i2=__shfl(myidx,k+2), i3=__shfl(myidx,k+3),
          i4=__shfl(myidx,k+4), i5=__shfl(myidx,k+5),
          i6=__shfl(myidx,k+6), i7=__shfl(myidx,k+7);
      float v0=srcv[i0*DD+lane], v1=srcv[i1*DD+lane],
            v2=srcv[i2*DD+lane], v3=srcv[i3*DD+lane],
            v4=srcv[i4*DD+lane], v5=srcv[i5*DD+lane],
            v6=srcv[i6*DD+lane], v7=srcv[i7*DD+lane];
      acc += ((v0+v1)+(v2+v3)) + ((v4+v5)+(v6+v7));
    }
    for(; k<kk; k++) acc += srcv[__shfl(myidx,k)*DD+lane];
  }
  float iv = inv[node];
  float outv = acc*iv;
  h[node*DD+lane] = outv;
  res[node*DD+lane] += outv;
  if(!last){
    hso[node*DD+lane] = outv*iv;
    return;
  }
  // ---- fused epilogue (layer 3): norms + pos dots ----
  const float SC = 14.426950408889634f;
  const float eps = 1e-12f;
  float ev = eX[node*DD+lane];
  float hn = wred64(outv*outv);
  float en = wred64(ev*ev);
  float ihn = 1.0f/fmaxf(sqrtf(hn), eps);
  float ien = 1.0f/fmaxf(sqrtf(en), eps);
  nc [node*DD+lane] = __float2bfloat16(outv*(SC*ihn));
  npv[node*DD+lane] = __float2bfloat16(ev  *(SC*ien));
  int c = n2c[idxX[node]];
  float cv = cent[c*DD+lane];
  float he = wred64(outv*ev);
  float cc = wred64(cv*cv);
  float ec = wred64(ev*cv);
  if(lane==0){
    float icn = 1.0f/fmaxf(sqrtf(cc), eps);
    posA[node] = he*ihn*ien;
    posB[node] = ec*ien*icn;
  }
}

// ---- fused MFMA exp-sum (z=0..3) + scores (z=4); 128 A-rows per wave ----
// R19-bench skeleton; inner loop now FULL c[8] split: all 16 MFMAs issue
// back-to-back (each MFMA's latency hidden behind 15 successors), then all
// 32 exps stream at trans rate overlapped with next-iter loads. +16 VGPR
// vs c[4] (~80 total, within the 128/wave budget at launch_bounds(256,4)).
// Same loads, same per-acc-element math order (bitwise identical).
// jchunk=512 -> 1208 working blocks. XCD-pinned decomposition:
// bid -> (g=bid/64, r=bid%64), y=8g+(r&7), x=r>>3.
// z=4 runs the pos/neg score pairs (memory-bound, backfills expsum drain).
// tot[b] += sum_j exp2(dot(A[b],B[j])), A pre-scaled by SC = 10*log2(e).
// B buffers have >=48 rows of slack past nBpad (depth-1 prefetch overrun).
struct EArg {
  const __hip_bfloat16* A; const __hip_bfloat16* B; float* tot;
  int nBpad; int jchunk; int ny;
};
struct SArg {
  const float* res_u; const float* res_i;
  const int* pu; const int* pv; const int* nu; const int* nv; float* out;
};
#define EGX 784

__global__ __launch_bounds__(256,4)
void k_expsum(EArg e0, EArg e1, EArg e2, EArg e3, SArg sc){
  if(blockIdx.z == 4){
    // ---- scores: 16 lanes per pair, grid-stride ----
    const int stride = EGX*256;
    const int limit = 2*NPRED*16;
    for(int t = blockIdx.x*256 + threadIdx.x; t < limit; t += stride){
      int pair = t >> 4;
      int sl = t & 15;
      int a,b;
      if(pair < NPRED){ a=sc.pu[pair]; b=sc.pv[pair]; }
      else { a=sc.nu[pair-NPRED]; b=sc.nv[pair-NPRED]; }
      f4 xu = *(const f4*)(sc.res_u + a*DD + sl*4);
      f4 xv = *(const f4*)(sc.res_i + b*DD + sl*4);
      float x = xu[0]*xv[0] + xu[1]*xv[1] + xu[2]*xv[2] + xu[3]*xv[3];
      x += __shfl_xor(x,1); x += __shfl_xor(x,2);
      x += __shfl_xor(x,4); x += __shfl_xor(x,8);
      if(sl==0) sc.out[pair] = x*(1.0f/16.0f);  // res divided by 4 each side
    }
    return;
  }
  EArg e = (blockIdx.z==0)? e0 : (blockIdx.z==1)? e1 : (blockIdx.z==2)? e2 : e3;
  int bid = blockIdx.x;
  int g = bid >> 6, r6 = bid & 63;
  int y = 8*g + (r6 & 7);
  int x = r6 >> 3;
  if(y >= e.ny) return;
  int wave = threadIdx.x >> 6;
  int lane = threadIdx.x & 63;
  int row0 = (x*4 + wave)*128;
  int j_begin = y*e.jchunk;
  int j_end = min(j_begin + e.jchunk, e.nBpad);
  int r = lane & 15, kq = (lane>>4)*8;

  sh8 a0[8], a1[8];
#pragma unroll
  for(int t=0;t<8;t++){
    const short* ap = (const short*)(e.A + (row0 + t*16 + r)*DD);
    a0[t] = *(const sh8*)(ap + kq);
    a1[t] = *(const sh8*)(ap + kq + 32);
  }
  float acc[8][4];
#pragma unroll
  for(int t=0;t<8;t++)
#pragma unroll
    for(int q=0;q<4;q++) acc[t][q]=0.f;

  const short* bbase = (const short*)e.B;
  const short* bp0 = bbase + (j_begin + r)*DD + kq;
  sh8 b0 = *(const sh8*)(bp0);
  sh8 b1 = *(const sh8*)(bp0 + 32);

#pragma unroll 2
  for(int j0=j_begin; j0<j_end; j0+=16){
    const short* np = bbase + (j0 + 16 + r)*DD + kq;   // prefetch next tile
    sh8 n0 = *(const sh8*)(np);
    sh8 n1 = *(const sh8*)(np + 32);
    // full split: 16 independent MFMAs, then 32 exps
    f4 c[8];
#pragma unroll
    for(int t=0;t<8;t++){
      f4 cc = {0.f,0.f,0.f,0.f};
      cc = __builtin_amdgcn_mfma_f32_16x16x32_bf16(a0[t], b0, cc, 0,0,0);
      c[t] = __builtin_amdgcn_mfma_f32_16x16x32_bf16(a1[t], b1, cc, 0,0,0);
    }
#pragma unroll
    for(int t=0;t<8;t++)
#pragma unroll
      for(int q=0;q<4;q++) acc[t][q] += fast_exp2(c[t][q]);
    b0 = n0; b1 = n1;
  }
#pragma unroll
  for(int t=0;t<8;t++){
#pragma unroll
    for(int q=0;q<4;q++){
      float v = acc[t][q];
      v += __shfl_xor(v,1); v += __shfl_xor(v,2);
      v += __shfl_xor(v,4); v += __shfl_xor(v,8);
      if(r==0) atomicAdd(&e.tot[row0 + t*16 + (lane>>4)*4 + q], v);
    }
  }
}

// ---- final losses (pad rows each contributed exp2(0)=1 -> subtract) ----
__global__ void k_loss(const float* __restrict__ tot4, const float* __restrict__ pos4,
                       float* out){
  const float PI_ = (float)(INUM_PAD-INUM);   // 8
  const float PK_ = (float)(KCL_PAD-KCL);     // 8
  float s0=0,s1=0,s2=0,s3=0;
  for(int b=threadIdx.x; b<NU; b+=256){
    s0 += logf(tot4[0*NU+b])       - 10.f*pos4[0*NU+b];
    s1 += logf(tot4[1*NU+b] - PI_) - 10.f*pos4[1*NU+b];
    s2 += logf(tot4[2*NU+b] - PK_) - 10.f*pos4[2*NU+b];
    s3 += logf(tot4[3*NU+b] - PK_) - 10.f*pos4[3*NU+b];
  }
  s0=wred64(s0); s1=wred64(s1); s2=wred64(s2); s3=wred64(s3);
  __shared__ float ls[4][4];
  int lane=threadIdx.x&63, w=threadIdx.x>>6;
  if(lane==0){ ls[w][0]=s0; ls[w][1]=s1; ls[w][2]=s2; ls[w][3]=s3; }
  __syncthreads();
  if(threadIdx.x==0){
    float a=0,b2=0,c=0,d=0;
#pragma unroll
    for(int k=0;k<4;k++){ a+=ls[k][0]; b2+=ls[k][1]; c+=ls[k][2]; d+=ls[k][3]; }
    out[2*NPRED]   = 1e-6f*(a+b2);
    out[2*NPRED+1] = 8e-8f*(c+d);
  }
}

extern "C" void kernel_launch(void* const* d_in, const int* in_sizes, int n_in,
                              void* d_out, int out_size, void* d_ws, size_t ws_size,
                              hipStream_t stream) {
  const float* emb_user = (const float*)d_in[0];
  const float* emb_item = (const float*)d_in[1];
  const float* ucent    = (const float*)d_in[2];
  const float* icent    = (const float*)d_in[3];
  const int* edge_u = (const int*)d_in[4];
  const int* edge_v = (const int*)d_in[5];
  const int* pos_u  = (const int*)d_in[6];
  const int* pos_v  = (const int*)d_in[7];
  const int* neg_u  = (const int*)d_in[8];
  const int* neg_v  = (const int*)d_in[9];
  const int* idx_u  = (const int*)d_in[10];
  const int* idx_i  = (const int*)d_in[11];
  const int* u2c    = (const int*)d_in[12];
  const int* i2c    = (const int*)d_in[13];
  float* out = (float*)d_out;

  char* w = (char*)d_ws;
  auto alloc = [&](size_t bytes)->void*{
    void* p = (void*)w;
    w += (bytes + 255) & ~(size_t)255;
    return p;
  };
  int* cnt_u = (int*)alloc(NU*4);            // contiguous with cnt_i: one memset
  int* cnt_i = (int*)alloc(NI*4);
  int* rp_u  = (int*)alloc((NU+1)*4);
  int* rp_i  = (int*)alloc((NI+1)*4);
  int* cur_u = (int*)alloc(NU*4);
  int* cur_i = (int*)alloc(NI*4);
  int* adj_u = (int*)alloc((size_t)NE*4);
  int* adj_i = (int*)alloc((size_t)NE*4);
  float* inv_u = (float*)alloc(NU*4);
  float* inv_i = (float*)alloc(NI*4);
  float* e_u  = (float*)alloc((size_t)NU*DD*4);
  float* e_i  = (float*)alloc((size_t)NI*DD*4);
  float* h_u  = (float*)alloc((size_t)NU*DD*4);
  float* h_i  = (float*)alloc((size_t)NI*DD*4);
  float* hsA_u = (float*)alloc((size_t)NU*DD*4);
  float* hsA_i = (float*)alloc((size_t)NI*DD*4);
  float* hsB_u = (float*)alloc((size_t)NU*DD*4);
  float* hsB_i = (float*)alloc((size_t)NI*DD*4);
  float* res_u= (float*)alloc((size_t)NU*DD*4);
  float* res_i= (float*)alloc((size_t)NI*DD*4);
  // B-side bf16 buffers: +48 rows slack for depth-1 prefetch overrun
  __hip_bfloat16* ntb_user = (__hip_bfloat16*)alloc((size_t)(UNUM+48)*DD*2);
  __hip_bfloat16* ntb_item = (__hip_bfloat16*)alloc((size_t)(INUM_PAD+48)*DD*2);
  __hip_bfloat16* ncb_u = (__hip_bfloat16*)alloc((size_t)(KCL_PAD+48)*DD*2);
  __hip_bfloat16* ncb_i = (__hip_bfloat16*)alloc((size_t)(KCL_PAD+48)*DD*2);
  __hip_bfloat16* nc_u  = (__hip_bfloat16*)alloc((size_t)NU*DD*2);
  __hip_bfloat16* nc_i  = (__hip_bfloat16*)alloc((size_t)NI*DD*2);
  __hip_bfloat16* npv_u = (__hip_bfloat16*)alloc((size_t)NU*DD*2);
  __hip_bfloat16* npv_i = (__hip_bfloat16*)alloc((size_t)NI*DD*2);
  float* tot4 = (float*)alloc(4*NU*4);
  float* pos4 = (float*)alloc(4*NU*4);

  hipMemsetAsync(cnt_u, 0, 2*NU*4, stream);  // cnt_u + cnt_i contiguous

  k_histnorm<<<HN3, 256, 0, stream>>>(edge_u, edge_v, cnt_u, cnt_i,
                                      emb_user, emb_item, ucent, icent,
                                      ntb_user, ntb_item, ncb_u, ncb_i);
  k_scan<<<2, 1024, 0, stream>>>(cnt_u, rp_u, cur_u, inv_u,
                                 cnt_i, rp_i, cur_i, inv_i, tot4);
  k_fillgather<<<3072, 256, 0, stream>>>(edge_u, edge_v, cur_u, cur_i, adj_u, adj_i,
                                         emb_user, emb_item, idx_u, idx_i,
                                         inv_u, inv_i,
                                         e_u, e_i, res_u, res_i, hsA_u, hsA_i);
  // layer 0: A->B; layer 1: B->A; layer 2 (last): A->(h,res,norms,pos)
  k_conv<<<(NU+NI)/4, 256, 0, stream>>>(rp_i, adj_i, hsA_u, inv_i, h_i, res_i, hsB_i,
                                        rp_u, adj_u, hsA_i, inv_u, h_u, res_u, hsB_u,
                                        e_u, e_i, ucent, icent, idx_u, idx_i, u2c, i2c,
                                        nc_u, nc_i, npv_u, npv_i, pos4, 0);
  k_conv<<<(NU+NI)/4, 256, 0, stream>>>(rp_i, adj_i, hsB_u, inv_i, h_i, res_i, hsA_i,
                                        rp_u, adj_u, hsB_i, inv_u, h_u, res_u, hsA_u,
                                        e_u, e_i, ucent, icent, idx_u, idx_i, u2c, i2c,
                                        nc_u, nc_i, npv_u, npv_i, pos4, 0);
  k_conv<<<(NU+NI)/4, 256, 0, stream>>>(rp_i, adj_i, hsA_u, inv_i, h_i, res_i, hsB_i,
                                        rp_u, adj_u, hsA_i, inv_u, h_u, res_u, hsB_u,
                                        e_u, e_i, ucent, icent, idx_u, idx_i, u2c, i2c,
                                        nc_u, nc_i, npv_u, npv_i, pos4, 1);

  // fused 4-segment exp-sum (z=0..3) + scores (z=4)
  EArg eu_ = { nc_u,  ntb_user, tot4 + 0*NU, UNUM,     512, 98 };
  EArg ei_ = { nc_i,  ntb_item, tot4 + 1*NU, INUM_PAD, 512, 49 };
  EArg ep0 = { npv_u, ncb_u,    tot4 + 2*NU, KCL_PAD,  48,  21 };
  EArg ep1 = { npv_i, ncb_i,    tot4 + 3*NU, KCL_PAD,  48,  21 };
  SArg sc  = { res_u, res_i, pos_u, pos_v, neg_u, neg_v, out };
  k_expsum<<<dim3(EGX,1,5), 256, 0, stream>>>(eu_, ei_, ep0, ep1, sc);

  k_loss<<<1, 256, 0, stream>>>(tot4, pos4, out);
}

// Round 22
// 209.509 us; speedup vs baseline: 4.3898x; 1.4305x over previous
//
#include <hip/hip_runtime.h>
#include <hip/hip_bf16.h>

#define NU 4096
#define NI 4096
#define NE 262144
#define NPRED 65536
#define DD 64
#define KCL 1000
#define UNUM 50000
#define INUM 25000
#define INUM_PAD 25008
#define KCL_PAD 1008

typedef short sh8 __attribute__((ext_vector_type(8)));
typedef float f4 __attribute__((ext_vector_type(4)));

__device__ __forceinline__ float wred64(float x){
#pragma unroll
  for(int m=1;m<64;m<<=1) x += __shfl_xor(x,m);
  return x;
}

__device__ __forceinline__ float fast_exp2(float x){
  return __builtin_amdgcn_exp2f(x);
}

// ---- fused: degree histogram (blocks 0..1023) + static-table norms ----
#define HB 1024
#define HN0 (HB+12500)        // ntb_user  (50000 rows /4)
#define HN1 (HN0+6252)        // ntb_item  (25008 padded /4)
#define HN2 (HN1+252)         // ncb_u     (1008 padded /4)
#define HN3 (HN2+252)         // ncb_i     (1008 padded /4)

__global__ void k_histnorm(const int* __restrict__ eu, const int* __restrict__ ev,
                           int* cu, int* ci,
                           const float* __restrict__ emb_u, const float* __restrict__ emb_i,
                           const float* __restrict__ ucent, const float* __restrict__ icent,
                           __hip_bfloat16* ntb_u, __hip_bfloat16* ntb_i,
                           __hip_bfloat16* ncb_u, __hip_bfloat16* ncb_i){
  int b = blockIdx.x;
  if(b < HB){
    int t = b*256 + threadIdx.x;
    atomicAdd(&cu[eu[t]],1); atomicAdd(&ci[ev[t]],1);
    return;
  }
  const float* in; __hip_bfloat16* outp; int rows; int base;
  if(b < HN0)      { in=emb_u; outp=ntb_u; rows=UNUM; base=HB; }
  else if(b < HN1) { in=emb_i; outp=ntb_i; rows=INUM; base=HN0; }
  else if(b < HN2) { in=ucent; outp=ncb_u; rows=KCL;  base=HN1; }
  else             { in=icent; outp=ncb_i; rows=KCL;  base=HN2; }
  int row = (b-base)*4 + (threadIdx.x>>6);
  int lane = threadIdx.x & 63;
  if(row >= rows){ outp[row*DD + lane] = __float2bfloat16(0.f); return; }
  float v = in[row*DD + lane];
  float s = wred64(v*v);
  float sc = 1.0f / fmaxf(sqrtf(s), 1e-12f);
  outp[row*DD + lane] = __float2bfloat16(v*sc);
}

// ---- exclusive scan over 4096 counts (one block per side) + tot4 zeroing ----
__global__ void k_scan(const int* cnt_u, int* rp_u, int* cur_u, float* inv_u,
                       const int* cnt_i, int* rp_i, int* cur_i, float* inv_i,
                       float* tot4){
  {
    int base = blockIdx.x*8192 + threadIdx.x*8;
#pragma unroll
    for(int k=0;k<8;k++) tot4[base+k] = 0.f;
  }
  const int* cnt = blockIdx.x ? cnt_i : cnt_u;
  int* rp  = blockIdx.x ? rp_i  : rp_u;
  int* cur = blockIdx.x ? cur_i : cur_u;
  float* inv = blockIdx.x ? inv_i : inv_u;
  __shared__ int sdata[1024];
  int tid = threadIdx.x;
  int v[4]; int s = 0;
#pragma unroll
  for(int k=0;k<4;k++){ v[k]=cnt[tid*4+k]; s+=v[k]; }
  sdata[tid]=s; __syncthreads();
  for(int off=1; off<1024; off<<=1){
    int add = (tid>=off)? sdata[tid-off] : 0;
    __syncthreads();
    if(tid>=off) sdata[tid] += add;
    __syncthreads();
  }
  int run = sdata[tid]-s;   // exclusive base
#pragma unroll
  for(int k=0;k<4;k++){
    int idx = tid*4+k;
    rp[idx]=run; cur[idx]=run;
    inv[idx] = 1.0f/sqrtf(fmaxf((float)v[k],1.0f));
    run += v[k];
  }
  if(tid==1023) rp[4096]=run;
}

// ---- fused CSR fill (blocks 0..1023) + gather/init (blocks 1024..3071) ----
__global__ void k_fillgather(const int* __restrict__ eu, const int* __restrict__ ev,
                             int* cur_u, int* cur_i, int* adj_u, int* adj_i,
                             const float* __restrict__ emb_u, const float* __restrict__ emb_i,
                             const int* __restrict__ idx_u, const int* __restrict__ idx_i,
                             const float* __restrict__ inv_u, const float* __restrict__ inv_i,
                             float* e_u, float* e_i, float* res_u, float* res_i,
                             float* hs_u, float* hs_i){
  int b = blockIdx.x;
  if(b < 1024){
    int t = b*256 + threadIdx.x;
    int u=eu[t], v=ev[t];
    adj_u[atomicAdd(&cur_u[u],1)] = v;
    adj_i[atomicAdd(&cur_i[v],1)] = u;
  } else {
    int t = (b-1024)*256 + threadIdx.x;
    const int half = NU*DD;
    if(t < half){
      int r=t>>6;
      float v = emb_u[idx_u[r]*DD + (t&63)];
      e_u[t]=v; res_u[t]=v; hs_u[t]=v*inv_u[r];
    } else {
      int s=t-half; int r=s>>6;
      float v = emb_i[idx_i[r]*DD + (s&63)];
      e_i[s]=v; res_i[s]=v; hs_i[s]=v*inv_i[r];
    }
  }
}

// ---- pull-style conv: 4 waves per block, one node per wave ----
// adj content differs call-to-call (atomic fill order), so adj MUST be read
// through the vector path (coalesced per-lane load + shfl broadcast), never
// scalar s_load (K$ staleness across graph replays = nondeterministic output).
// last=1 (layer 3): fused epilogue computes nc (SC*normalize(h)),
// npv (SC*normalize(e)) and this side's pos4 entries; skips hs_next write.
__global__ void k_conv(const int* __restrict__ rp_i, const int* __restrict__ adj_i,
                       const float* __restrict__ hsu_in, const float* __restrict__ inv_i,
                       float* h_i, float* res_i, float* hsi_out,
                       const int* __restrict__ rp_u, const int* __restrict__ adj_u,
                       const float* __restrict__ hsi_in, const float* __restrict__ inv_u,
                       float* h_u, float* res_u, float* hsu_out,
                       const float* __restrict__ e_u, const float* __restrict__ e_i,
                       const float* __restrict__ ucent, const float* __restrict__ icent,
                       const int* __restrict__ idx_u, const int* __restrict__ idx_i,
                       const int* __restrict__ u2c, const int* __restrict__ i2c,
                       __hip_bfloat16* nc_u, __hip_bfloat16* nc_i,
                       __hip_bfloat16* npv_u, __hip_bfloat16* npv_i,
                       float* pos4, int last){
  int b = blockIdx.x*4 + (threadIdx.x>>6);
  int lane = threadIdx.x & 63;
  const int* rp; const int* adj; const float* srcv; const float* inv;
  float *h, *res, *hso; int node;
  const float* eX; const float* cent; const int* idxX; const int* n2c;
  __hip_bfloat16 *nc, *npv; float *posA, *posB;
  if(b < NI){
    rp=rp_i; adj=adj_i; srcv=hsu_in; inv=inv_i; h=h_i; res=res_i; hso=hsi_out; node=b;
    eX=e_i; cent=icent; idxX=idx_i; n2c=i2c; nc=nc_i; npv=npv_i;
    posA=pos4+1*NU; posB=pos4+3*NU;
  } else {
    node=b-NI; rp=rp_u; adj=adj_u; srcv=hsi_in; inv=inv_u; h=h_u; res=res_u; hso=hsu_out;
    eX=e_u; cent=ucent; idxX=idx_u; n2c=u2c; nc=nc_u; npv=npv_u;
    posA=pos4+0*NU; posB=pos4+2*NU;
  }
  int s=rp[node], e=rp[node+1];
  float acc=0.f;
  for(int base=s; base<e; base+=64){
    int m = e-base;
    int myidx = adj[base + min(lane, m-1)];   // one coalesced vector load / 64 edges
    int kk = min(64, m);
    int k=0;
    for(; k+8<=kk; k+=8){
      int i0=__shfl(myidx,k  ), i1=__shfl(myidx,k+1),
          i2=__shfl(myidx,k+2), i3=__shfl(myidx,k+3),
          i4=__shfl(myidx,k+4), i5=__shfl(myidx,k+5),
          i6=__shfl(myidx,k+6), i7=__shfl(myidx,k+7);
      float v0=srcv[i0*DD+lane], v1=srcv[i1*DD+lane],
            v2=srcv[i2*DD+lane], v3=srcv[i3*DD+lane],
            v4=srcv[i4*DD+lane], v5=srcv[i5*DD+lane],
            v6=srcv[i6*DD+lane], v7=srcv[i7*DD+lane];
      acc += ((v0+v1)+(v2+v3)) + ((v4+v5)+(v6+v7));
    }
    for(; k<kk; k++) acc += srcv[__shfl(myidx,k)*DD+lane];
  }
  float iv = inv[node];
  float outv = acc*iv;
  h[node*DD+lane] = outv;
  res[node*DD+lane] += outv;
  if(!last){
    hso[node*DD+lane] = outv*iv;
    return;
  }
  // ---- fused epilogue (layer 3): norms + pos dots ----
  const float SC = 14.426950408889634f;
  const float eps = 1e-12f;
  float ev = eX[node*DD+lane];
  float hn = wred64(outv*outv);
  float en = wred64(ev*ev);
  float ihn = 1.0f/fmaxf(sqrtf(hn), eps);
  float ien = 1.0f/fmaxf(sqrtf(en), eps);
  nc [node*DD+lane] = __float2bfloat16(outv*(SC*ihn));
  npv[node*DD+lane] = __float2bfloat16(ev  *(SC*ien));
  int c = n2c[idxX[node]];
  float cv = cent[c*DD+lane];
  float he = wred64(outv*ev);
  float cc = wred64(cv*cv);
  float ec = wred64(ev*cv);
  if(lane==0){
    float icn = 1.0f/fmaxf(sqrtf(cc), eps);
    posA[node] = he*ihn*ien;
    posB[node] = ec*ien*icn;
  }
}

// ---- fused MFMA exp-sum (z=0..3) + scores (z=4); 128 A-rows per wave ----
// R19-bench version (banked best: expsum 74.5us, total 210.2us).
// Two t-halves with explicit c[4]: 8 independent MFMAs issue back-to-back,
// then 16 exps stream at trans rate. c[8] full split SPILLS (R20: WRITE_SIZE
// 13.7->36MB, expsum 177+us) -- c[4] is the no-spill ILP sweet spot at 64 VGPR.
// jchunk=512 -> 1208 working blocks. XCD-pinned decomposition:
// bid -> (g=bid/64, r=bid%64), y=8g+(r&7), x=r>>3.
// z=4 runs the pos/neg score pairs (memory-bound, backfills expsum drain).
// tot[b] += sum_j exp2(dot(A[b],B[j])), A pre-scaled by SC = 10*log2(e).
// B buffers have >=48 rows of slack past nBpad (depth-1 prefetch overrun).
struct EArg {
  const __hip_bfloat16* A; const __hip_bfloat16* B; float* tot;
  int nBpad; int jchunk; int ny;
};
struct SArg {
  const float* res_u; const float* res_i;
  const int* pu; const int* pv; const int* nu; const int* nv; float* out;
};
#define EGX 784

__global__ __launch_bounds__(256,4)
void k_expsum(EArg e0, EArg e1, EArg e2, EArg e3, SArg sc){
  if(blockIdx.z == 4){
    // ---- scores: 16 lanes per pair, grid-stride ----
    const int stride = EGX*256;
    const int limit = 2*NPRED*16;
    for(int t = blockIdx.x*256 + threadIdx.x; t < limit; t += stride){
      int pair = t >> 4;
      int sl = t & 15;
      int a,b;
      if(pair < NPRED){ a=sc.pu[pair]; b=sc.pv[pair]; }
      else { a=sc.nu[pair-NPRED]; b=sc.nv[pair-NPRED]; }
      f4 xu = *(const f4*)(sc.res_u + a*DD + sl*4);
      f4 xv = *(const f4*)(sc.res_i + b*DD + sl*4);
      float x = xu[0]*xv[0] + xu[1]*xv[1] + xu[2]*xv[2] + xu[3]*xv[3];
      x += __shfl_xor(x,1); x += __shfl_xor(x,2);
      x += __shfl_xor(x,4); x += __shfl_xor(x,8);
      if(sl==0) sc.out[pair] = x*(1.0f/16.0f);  // res divided by 4 each side
    }
    return;
  }
  EArg e = (blockIdx.z==0)? e0 : (blockIdx.z==1)? e1 : (blockIdx.z==2)? e2 : e3;
  int bid = blockIdx.x;
  int g = bid >> 6, r6 = bid & 63;
  int y = 8*g + (r6 & 7);
  int x = r6 >> 3;
  if(y >= e.ny) return;
  int wave = threadIdx.x >> 6;
  int lane = threadIdx.x & 63;
  int row0 = (x*4 + wave)*128;
  int j_begin = y*e.jchunk;
  int j_end = min(j_begin + e.jchunk, e.nBpad);
  int r = lane & 15, kq = (lane>>4)*8;

  sh8 a0[8], a1[8];
#pragma unroll
  for(int t=0;t<8;t++){
    const short* ap = (const short*)(e.A + (row0 + t*16 + r)*DD);
    a0[t] = *(const sh8*)(ap + kq);
    a1[t] = *(const sh8*)(ap + kq + 32);
  }
  float acc[8][4];
#pragma unroll
  for(int t=0;t<8;t++)
#pragma unroll
    for(int q=0;q<4;q++) acc[t][q]=0.f;

  const short* bbase = (const short*)e.B;
  const short* bp0 = bbase + (j_begin + r)*DD + kq;
  sh8 b0 = *(const sh8*)(bp0);
  sh8 b1 = *(const sh8*)(bp0 + 32);

#pragma unroll 2
  for(int j0=j_begin; j0<j_end; j0+=16){
    const short* np = bbase + (j0 + 16 + r)*DD + kq;   // prefetch next tile
    sh8 n0 = *(const sh8*)(np);
    sh8 n1 = *(const sh8*)(np + 32);
    // half 1: t = 0..3 — 8 independent MFMAs, then 16 exps
    {
      f4 c[4];
#pragma unroll
      for(int t=0;t<4;t++){
        f4 cc = {0.f,0.f,0.f,0.f};
        cc = __builtin_amdgcn_mfma_f32_16x16x32_bf16(a0[t], b0, cc, 0,0,0);
        c[t] = __builtin_amdgcn_mfma_f32_16x16x32_bf16(a1[t], b1, cc, 0,0,0);
      }
#pragma unroll
      for(int t=0;t<4;t++)
#pragma unroll
        for(int q=0;q<4;q++) acc[t][q] += fast_exp2(c[t][q]);
    }
    // half 2: t = 4..7
    {
      f4 c[4];
#pragma unroll
      for(int t=0;t<4;t++){
        f4 cc = {0.f,0.f,0.f,0.f};
        cc = __builtin_amdgcn_mfma_f32_16x16x32_bf16(a0[t+4], b0, cc, 0,0,0);
        c[t] = __builtin_amdgcn_mfma_f32_16x16x32_bf16(a1[t+4], b1, cc, 0,0,0);
      }
#pragma unroll
      for(int t=0;t<4;t++)
#pragma unroll
        for(int q=0;q<4;q++) acc[t+4][q] += fast_exp2(c[t][q]);
    }
    b0 = n0; b1 = n1;
  }
#pragma unroll
  for(int t=0;t<8;t++){
#pragma unroll
    for(int q=0;q<4;q++){
      float v = acc[t][q];
      v += __shfl_xor(v,1); v += __shfl_xor(v,2);
      v += __shfl_xor(v,4); v += __shfl_xor(v,8);
      if(r==0) atomicAdd(&e.tot[row0 + t*16 + (lane>>4)*4 + q], v);
    }
  }
}

// ---- final losses (pad rows each contributed exp2(0)=1 -> subtract) ----
__global__ void k_loss(const float* __restrict__ tot4, const float* __restrict__ pos4,
                       float* out){
  const float PI_ = (float)(INUM_PAD-INUM);   // 8
  const float PK_ = (float)(KCL_PAD-KCL);     // 8
  float s0=0,s1=0,s2=0,s3=0;
  for(int b=threadIdx.x; b<NU; b+=256){
    s0 += logf(tot4[0*NU+b])       - 10.f*pos4[0*NU+b];
    s1 += logf(tot4[1*NU+b] - PI_) - 10.f*pos4[1*NU+b];
    s2 += logf(tot4[2*NU+b] - PK_) - 10.f*pos4[2*NU+b];
    s3 += logf(tot4[3*NU+b] - PK_) - 10.f*pos4[3*NU+b];
  }
  s0=wred64(s0); s1=wred64(s1); s2=wred64(s2); s3=wred64(s3);
  __shared__ float ls[4][4];
  int lane=threadIdx.x&63, w=threadIdx.x>>6;
  if(lane==0){ ls[w][0]=s0; ls[w][1]=s1; ls[w][2]=s2; ls[w][3]=s3; }
  __syncthreads();
  if(threadIdx.x==0){
    float a=0,b2=0,c=0,d=0;
#pragma unroll
    for(int k=0;k<4;k++){ a+=ls[k][0]; b2+=ls[k][1]; c+=ls[k][2]; d+=ls[k][3]; }
    out[2*NPRED]   = 1e-6f*(a+b2);
    out[2*NPRED+1] = 8e-8f*(c+d);
  }
}

extern "C" void kernel_launch(void* const* d_in, const int* in_sizes, int n_in,
                              void* d_out, int out_size, void* d_ws, size_t ws_size,
                              hipStream_t stream) {
  const float* emb_user = (const float*)d_in[0];
  const float* emb_item = (const float*)d_in[1];
  const float* ucent    = (const float*)d_in[2];
  const float* icent    = (const float*)d_in[3];
  const int* edge_u = (const int*)d_in[4];
  const int* edge_v = (const int*)d_in[5];
  const int* pos_u  = (const int*)d_in[6];
  const int* pos_v  = (const int*)d_in[7];
  const int* neg_u  = (const int*)d_in[8];
  const int* neg_v  = (const int*)d_in[9];
  const int* idx_u  = (const int*)d_in[10];
  const int* idx_i  = (const int*)d_in[11];
  const int* u2c    = (const int*)d_in[12];
  const int* i2c    = (const int*)d_in[13];
  float* out = (float*)d_out;

  char* w = (char*)d_ws;
  auto alloc = [&](size_t bytes)->void*{
    void* p = (void*)w;
    w += (bytes + 255) & ~(size_t)255;
    return p;
  };
  int* cnt_u = (int*)alloc(NU*4);            // contiguous with cnt_i: one memset
  int* cnt_i = (int*)alloc(NI*4);
  int* rp_u  = (int*)alloc((NU+1)*4);
  int* rp_i  = (int*)alloc((NI+1)*4);
  int* cur_u = (int*)alloc(NU*4);
  int* cur_i = (int*)alloc(NI*4);
  int* adj_u = (int*)alloc((size_t)NE*4);
  int* adj_i = (int*)alloc((size_t)NE*4);
  float* inv_u = (float*)alloc(NU*4);
  float* inv_i = (float*)alloc(NI*4);
  float* e_u  = (float*)alloc((size_t)NU*DD*4);
  float* e_i  = (float*)alloc((size_t)NI*DD*4);
  float* h_u  = (float*)alloc((size_t)NU*DD*4);
  float* h_i  = (float*)alloc((size_t)NI*DD*4);
  float* hsA_u = (float*)alloc((size_t)NU*DD*4);
  float* hsA_i = (float*)alloc((size_t)NI*DD*4);
  float* hsB_u = (float*)alloc((size_t)NU*DD*4);
  float* hsB_i = (float*)alloc((size_t)NI*DD*4);
  float* res_u= (float*)alloc((size_t)NU*DD*4);
  float* res_i= (float*)alloc((size_t)NI*DD*4);
  // B-side bf16 buffers: +48 rows slack for depth-1 prefetch overrun
  __hip_bfloat16* ntb_user = (__hip_bfloat16*)alloc((size_t)(UNUM+48)*DD*2);
  __hip_bfloat16* ntb_item = (__hip_bfloat16*)alloc((size_t)(INUM_PAD+48)*DD*2);
  __hip_bfloat16* ncb_u = (__hip_bfloat16*)alloc((size_t)(KCL_PAD+48)*DD*2);
  __hip_bfloat16* ncb_i = (__hip_bfloat16*)alloc((size_t)(KCL_PAD+48)*DD*2);
  __hip_bfloat16* nc_u  = (__hip_bfloat16*)alloc((size_t)NU*DD*2);
  __hip_bfloat16* nc_i  = (__hip_bfloat16*)alloc((size_t)NI*DD*2);
  __hip_bfloat16* npv_u = (__hip_bfloat16*)alloc((size_t)NU*DD*2);
  __hip_bfloat16* npv_i = (__hip_bfloat16*)alloc((size_t)NI*DD*2);
  float* tot4 = (float*)alloc(4*NU*4);
  float* pos4 = (float*)alloc(4*NU*4);

  hipMemsetAsync(cnt_u, 0, 2*NU*4, stream);  // cnt_u + cnt_i contiguous

  k_histnorm<<<HN3, 256, 0, stream>>>(edge_u, edge_v, cnt_u, cnt_i,
                                      emb_user, emb_item, ucent, icent,
                                      ntb_user, ntb_item, ncb_u, ncb_i);
  k_scan<<<2, 1024, 0, stream>>>(cnt_u, rp_u, cur_u, inv_u,
                                 cnt_i, rp_i, cur_i, inv_i, tot4);
  k_fillgather<<<3072, 256, 0, stream>>>(edge_u, edge_v, cur_u, cur_i, adj_u, adj_i,
                                         emb_user, emb_item, idx_u, idx_i,
                                         inv_u, inv_i,
                                         e_u, e_i, res_u, res_i, hsA_u, hsA_i);
  // layer 0: A->B; layer 1: B->A; layer 2 (last): A->(h,res,norms,pos)
  k_conv<<<(NU+NI)/4, 256, 0, stream>>>(rp_i, adj_i, hsA_u, inv_i, h_i, res_i, hsB_i,
                                        rp_u, adj_u, hsA_i, inv_u, h_u, res_u, hsB_u,
                                        e_u, e_i, ucent, icent, idx_u, idx_i, u2c, i2c,
                                        nc_u, nc_i, npv_u, npv_i, pos4, 0);
  k_conv<<<(NU+NI)/4, 256, 0, stream>>>(rp_i, adj_i, hsB_u, inv_i, h_i, res_i, hsA_i,
                                        rp_u, adj_u, hsB_i, inv_u, h_u, res_u, hsA_u,
                                        e_u, e_i, ucent, icent, idx_u, idx_i, u2c, i2c,
                                        nc_u, nc_i, npv_u, npv_i, pos4, 0);
  k_conv<<<(NU+NI)/4, 256, 0, stream>>>(rp_i, adj_i, hsA_u, inv_i, h_i, res_i, hsB_i,
                                        rp_u, adj_u, hsA_i, inv_u, h_u, res_u, hsB_u,
                                        e_u, e_i, ucent, icent, idx_u, idx_i, u2c, i2c,
                                        nc_u, nc_i, npv_u, npv_i, pos4, 1);

  // fused 4-segment exp-sum (z=0..3) + scores (z=4)
  EArg eu_ = { nc_u,  ntb_user, tot4 + 0*NU, UNUM,     512, 98 };
  EArg ei_ = { nc_i,  ntb_item, tot4 + 1*NU, INUM_PAD, 512, 49 };
  EArg ep0 = { npv_u, ncb_u,    tot4 + 2*NU, KCL_PAD,  48,  21 };
  EArg ep1 = { npv_i, ncb_i,    tot4 + 3*NU, KCL_PAD,  48,  21 };
  SArg sc  = { res_u, res_i, pos_u, pos_v, neg_u, neg_v, out };
  k_expsum<<<dim3(EGX,1,5), 256, 0, stream>>>(eu_, ei_, ep0, ep1, sc);

  k_loss<<<1, 256, 0, stream>>>(tot4, pos4, out);
}